// Round 12
// baseline (367.487 us; speedup 1.0000x reference)
//
#include <hip/hip_runtime.h>
#include <hip/hip_bf16.h>
#include <stdint.h>

#define HID   2048
#define NH    16
#define QKV_N 6144   // 16*(2*128+128)
#define QKP   4096   // pitch of qk_bf (Q|K only)
#define BT    8192   // B*T
#define TT    2048   // T

typedef short bf16x8  __attribute__((ext_vector_type(8)));
typedef float f32x4   __attribute__((ext_vector_type(4)));
typedef float f32x16  __attribute__((ext_vector_type(16)));
typedef unsigned short u16;

__device__ __forceinline__ u16 f2bf(float f){
  union { float f; unsigned u; } v; v.f = f;
  unsigned r = 0x7fffu + ((v.u >> 16) & 1u);
  return (u16)((v.u + r) >> 16);
}
__device__ __forceinline__ float bf2f(u16 x){
  union { unsigned u; float f; } v; v.u = ((unsigned)x) << 16;
  return v.f;
}
__device__ __forceinline__ unsigned cvt_pk_bf16(float lo, float hi){
  unsigned r;
  asm("v_cvt_pk_bf16_f32 %0, %1, %2" : "=v"(r) : "v"(lo), "v"(hi));
  return r;
}

typedef __attribute__((address_space(3))) void lds_vt;
typedef const __attribute__((address_space(1))) void gbl_vt;

__device__ __forceinline__ void gload16(const void* g, void* l){
  __builtin_amdgcn_global_load_lds((gbl_vt*)g, (lds_vt*)l, 16, 0, 0);
}

#define FENCE() asm volatile("" ::: "memory")
#define SYNC()  { FENCE(); __builtin_amdgcn_s_barrier(); FENCE(); }

// ---------------- fused fp32 -> bf16 convert (3 arrays, 1 launch) ----------------
__global__ __launch_bounds__(256) void cvt_all(const float* __restrict__ in1, u16* __restrict__ o1, int n1,
                                               const float* __restrict__ in2, u16* __restrict__ o2, int n2,
                                               const float* __restrict__ in3, u16* __restrict__ o3, int n3){
  int i = blockIdx.x * blockDim.x + threadIdx.x;
  const int stride = gridDim.x * blockDim.x;
  const int ntot = n1 + n2 + n3;
  for (; i < ntot; i += stride){
    const float* ip; u16* op; int k;
    if (i < n1)            { ip = in1; op = o1; k = i; }
    else if (i < n1 + n2)  { ip = in2; op = o2; k = i - n1; }
    else                   { ip = in3; op = o3; k = i - n1 - n2; }
    float4 v = ((const float4*)ip)[k];
    ushort4 o;
    o.x = f2bf(v.x); o.y = f2bf(v.y); o.z = f2bf(v.z); o.w = f2bf(v.w);
    ((ushort4*)op)[k] = o;
  }
}

// ---------------- 256x256 8-phase bf16 GEMM, C = A * B^T ----------------
// 16x16x32 core (known-good: 186us, MfmaUtil 50%, 0 conflicts).
// MODE 0: fp32 out + bias (pitch N). MODE 1: bf16 out, Q/K tiles (n0<4096) ->
// Cb pitch 4096; V tiles (n0>=4096) -> vt2 transposed-swizzled image (fused vtrans).
template<int MODE>
__global__ __launch_bounds__(512, 2) void gemm256(const u16* __restrict__ A,
                                                  const u16* __restrict__ Bm,
                                                  u16* __restrict__ Cb,
                                                  float* __restrict__ Cf,
                                                  const float* __restrict__ bias,
                                                  u16* __restrict__ vt2,
                                                  int M, int N, int K)
{
  __shared__ u16 lds[4 * 256 * 64];   // 128 KiB
  u16* const Abuf[2] = { lds,          lds + 16384 };
  u16* const Bbuf[2] = { lds + 32768,  lds + 49152 };

  const int tid  = threadIdx.x;
  const int w    = tid >> 6;
  const int lane = tid & 63;
  const int wm   = w >> 2;
  const int wn   = w & 3;
  const int lr   = lane & 15;
  const int lg   = lane >> 4;

  int bid = blockIdx.x;
  { int qq = gridDim.x >> 3; bid = (bid & 7) * qq + (bid >> 3); }
  const int ntile = N >> 8;
  const int m0 = (bid / ntile) << 8;
  const int n0 = (bid % ntile) << 8;

  const int rS = tid >> 3;
  const int cS = ((tid & 7) ^ (rS & 7)) * 8;
  const u16* gA = A  + (size_t)(m0 + rS) * K + cS;
  const u16* gB = Bm + (size_t)(n0 + rS) * K + cS;
  const int wds = w * 512;

  f32x4 acc[8][4] = {};
  bf16x8 aq[2][2], bq[4][2];

  auto stgA = [&](int buf, int half, int kt){
    const u16* s = gA + (size_t)(half * 128) * K + (size_t)kt * 64;
    gload16(s,                  Abuf[buf] + half * 8192 + wds);
    gload16(s + (size_t)64 * K, Abuf[buf] + half * 8192 + 4096 + wds);
  };
  auto stgB = [&](int buf, int half, int kt){
    const u16* s = gB + (size_t)(half * 128) * K + (size_t)kt * 64;
    gload16(s,                  Bbuf[buf] + half * 8192 + wds);
    gload16(s + (size_t)64 * K, Bbuf[buf] + half * 8192 + 4096 + wds);
  };
  auto loadA = [&](const u16* ab, int q){
    #pragma unroll
    for (int kk = 0; kk < 2; ++kk){
      #pragma unroll
      for (int mf2 = 0; mf2 < 2; ++mf2){
        int row = wm * 128 + (q * 2 + mf2) * 16 + lr;
        int blk = (kk * 4 + lg) ^ (lr & 7);
        aq[mf2][kk] = *(const bf16x8*)(ab + row * 64 + blk * 8);
      }
    }
  };
  auto loadB = [&](const u16* bb){
    #pragma unroll
    for (int nf = 0; nf < 4; ++nf){
      #pragma unroll
      for (int kk = 0; kk < 2; ++kk){
        int row = wn * 64 + nf * 16 + lr;
        int blk = (kk * 4 + lg) ^ (lr & 7);
        bq[nf][kk] = *(const bf16x8*)(bb + row * 64 + blk * 8);
      }
    }
  };

#define MFMAQ(Q) do {                                                         \
    __builtin_amdgcn_s_setprio(1);                                            \
    _Pragma("unroll")                                                         \
    for (int kk = 0; kk < 2; ++kk){                                           \
      _Pragma("unroll")                                                       \
      for (int mf2 = 0; mf2 < 2; ++mf2){                                      \
        _Pragma("unroll")                                                     \
        for (int nf = 0; nf < 4; ++nf)                                        \
          acc[(Q)*2+mf2][nf] = __builtin_amdgcn_mfma_f32_16x16x32_bf16(       \
              aq[mf2][kk], bq[nf][kk], acc[(Q)*2+mf2][nf], 0, 0, 0);          \
      }                                                                       \
    }                                                                         \
    __builtin_amdgcn_s_setprio(0);                                            \
  } while (0)

  stgA(0, 0, 0); stgA(0, 1, 0);
  stgB(0, 0, 0); stgB(0, 1, 0);
  stgB(1, 0, 1); stgB(1, 1, 1);
  asm volatile("s_waitcnt vmcnt(4)" ::: "memory");
  SYNC();

  const int NI = K >> 7;
  for (int it = 0; it < NI; ++it){
    const int t = it * 2;
    const bool lastI = (it == NI - 1);

    loadB(Bbuf[0]);
    loadA(Abuf[0], 0);
    stgA(1, 0, t + 1);
    SYNC(); MFMAQ(0); SYNC();

    loadA(Abuf[0], 1);
    stgA(1, 1, t + 1);
    SYNC(); MFMAQ(1); SYNC();

    loadA(Abuf[0], 2);
    if (!lastI) stgB(0, 0, t + 2);
    SYNC(); MFMAQ(2); SYNC();

    loadA(Abuf[0], 3);
    if (!lastI) stgB(0, 1, t + 2);
    SYNC(); MFMAQ(3);
    if (lastI) asm volatile("s_waitcnt vmcnt(0)" ::: "memory");
    else       asm volatile("s_waitcnt vmcnt(4)" ::: "memory");
    SYNC();

    loadB(Bbuf[1]);
    loadA(Abuf[1], 0);
    if (!lastI) stgA(0, 0, t + 2);
    SYNC(); MFMAQ(0); SYNC();

    loadA(Abuf[1], 1);
    if (!lastI) stgA(0, 1, t + 2);
    SYNC(); MFMAQ(1); SYNC();

    loadA(Abuf[1], 2);
    if (!lastI) stgB(1, 0, t + 3);
    SYNC(); MFMAQ(2); SYNC();

    loadA(Abuf[1], 3);
    if (!lastI) stgB(1, 1, t + 3);
    SYNC(); MFMAQ(3);
    if (!lastI) asm volatile("s_waitcnt vmcnt(4)" ::: "memory");
    SYNC();
  }
#undef MFMAQ

  // epilogue: D layout col = lane&15, row = (lane>>4)*4 + r
  const int orow = m0 + wm * 128 + lg * 4;
  const int ocol = n0 + wn * 64 + lr;

  if (MODE == 1 && n0 >= 4096){
    // fused V-transpose: write vt2[bh][t5] image (exact inverse of attn's reader)
    #pragma unroll
    for (int nf = 0; nf < 4; ++nf){
      const int c   = ocol + nf * 16 - 4096;   // 0..2047
      const int h2  = c >> 7;
      const int d   = c & 127;
      const int r64 = d & 63;
      const int hd  = d >> 6;
      #pragma unroll
      for (int mf = 0; mf < 8; ++mf)
        #pragma unroll
        for (int r = 0; r < 4; ++r){
          const int row = orow + mf * 16 + r;       // t_global
          const int bb  = row >> 11;
          const int t   = row & 2047;
          const int t5  = t >> 5;
          const int kv  = t & 31;
          const int sl  = hd * 4 + (kv >> 3);
          const int sp  = sl ^ (r64 & 7);
          vt2[(size_t)((bb * 16 + h2) * 64 + t5) * 4096 + r64 * 64 + sp * 8 + (kv & 7)]
              = f2bf(acc[mf][nf][r]);
        }
    }
  } else {
    #pragma unroll
    for (int mf = 0; mf < 8; ++mf)
      #pragma unroll
      for (int nf = 0; nf < 4; ++nf)
        #pragma unroll
        for (int r = 0; r < 4; ++r){
          int row = orow + mf * 16 + r;
          int col = ocol + nf * 16;
          float v = acc[mf][nf][r];
          if (MODE == 1)
            Cb[(size_t)row * QKP + col] = f2bf(v);
          else
            Cf[(size_t)row * N + col] = v + bias[col];
        }
  }
}

// ---------------- causal flash attention, swapped 32x32, 64-kv barrier windows ----------------
// grid (bh=64, 16); qt = 15-y. 4 waves x 32 q-rows. No max-tracking.
// Double-buffered 64-kv windows (K 2x16KB + V 2x16KB = 64KB, 2 blocks/CU):
// ONE barrier pair per 64 kv (halved); compute internals stay at verified
// 32-granularity (jj = 2j+s), prefetch depth 1 window (~1000 cyc cover).
__global__ __launch_bounds__(256, 2) void attn(const u16* __restrict__ qk,
                                               const u16* __restrict__ vt2,
                                               u16* __restrict__ aout)
{
  __shared__ u16 Kl[2][64 * 128];   // 32KB: rows j*64..+63, swizzled cols
  __shared__ u16 Vl[2][2][4096];    // 32KB: two 32-kv V images per window

  const int qt = 15 - (int)blockIdx.y;
  const int bh = blockIdx.x;
  const int b = bh >> 4, h = bh & 15;
  const int tid  = threadIdx.x;
  const int w    = tid >> 6;
  const int lane = tid & 63;
  const int l31  = lane & 31;
  const int hi   = lane >> 5;
  const int sw7  = l31 & 7;

  const int qg = qt * 128 + w * 32 + l31;   // this lane's q row
  const float sc2 = 0.08838834764831845f * 1.4426950408889634f;

  bf16x8 qf[8];
  {
    const u16* qp = qk + (size_t)(b * TT + qg) * QKP + h * 128 + hi * 8;
    #pragma unroll
    for (int s = 0; s < 8; ++s){
      bf16x8 raw = *(const bf16x8*)(qp + s * 16);
      unsigned pk[4];
      #pragma unroll
      for (int p2 = 0; p2 < 4; ++p2)
        pk[p2] = cvt_pk_bf16(bf2f((u16)raw[2 * p2]) * sc2,
                             bf2f((u16)raw[2 * p2 + 1]) * sc2);
      int4 u = { (int)pk[0], (int)pk[1], (int)pk[2], (int)pk[3] };
      qf[s] = *(bf16x8*)&u;
    }
  }

  f32x16 o[4] = {};
  float lsum = 0.f;

  const u16* ksrc = qk + (size_t)(b * TT + (tid >> 4)) * QKP + 2048 + h * 128
                    + (((tid & 15) ^ ((tid >> 4) & 7)) * 8);
  const u16* vsrc = vt2 + (size_t)bh * (64 * 4096) + tid * 8;

  // stage one 64-kv window: K rows j*64..+63 (4 insts), V images t5=2j,2j+1 (4 insts)
  auto stage = [&](int buf, int j){
    const u16* ks = ksrc + (size_t)(j * 64) * QKP;
    #pragma unroll
    for (int i = 0; i < 4; ++i)
      gload16(ks + (size_t)(i * 16) * QKP, &Kl[buf][i * 2048 + tid * 8]);
    const u16* vs = vsrc + (size_t)(2 * j) * 4096;
    #pragma unroll
    for (int s = 0; s < 2; ++s){
      gload16(vs + s * 4096,        &Vl[buf][s][tid * 8]);
      gload16(vs + s * 4096 + 2048, &Vl[buf][s][2048 + tid * 8]);
    }
  };

  const int NT    = 2 * qt + 2;     // 64-kv windows
  const int jme32 = qt * 4 + w;     // 32-granular diagonal index (as before)
  stage(0, 0);

  for (int j = 0; j < NT; ++j){
    const int cur = j & 1;
    SYNC();                                   // B1: compute(j-1) done everywhere
    if (j + 1 < NT){
      stage(cur ^ 1, j + 1);
      asm volatile("s_waitcnt vmcnt(8)" ::: "memory");   // stage(j) landed
    } else {
      asm volatile("s_waitcnt vmcnt(0)" ::: "memory");
    }
    SYNC();                                   // B2: buf[cur] visible

    #pragma unroll
    for (int sb = 0; sb < 2; ++sb){
      const int jj = 2 * j + sb;              // 32-kv sub-tile index
      if (jj <= jme32){
        f32x16 sa = {}, sbv = {};
        const u16* KB = &Kl[cur][sb * 4096];
        __builtin_amdgcn_s_setprio(1);
        #pragma unroll
        for (int sl = 0; sl < 4; ++sl){
          const int spa = ((sl * 2 + hi) ^ sw7) * 8;
          const int spb = (((sl + 4) * 2 + hi) ^ sw7) * 8;
          bf16x8 ka  = *(const bf16x8*)(KB + l31 * 128 + spa);
          bf16x8 kb2 = *(const bf16x8*)(KB + l31 * 128 + spb);
          sa  = __builtin_amdgcn_mfma_f32_32x32x16_bf16(ka,  qf[sl],     sa,  0, 0, 0);
          sbv = __builtin_amdgcn_mfma_f32_32x32x16_bf16(kb2, qf[sl + 4], sbv, 0, 0, 0);
        }
        __builtin_amdgcn_s_setprio(0);

        f32x16 s;
        #pragma unroll
        for (int r = 0; r < 16; ++r) s[r] = sa[r] + sbv[r];

        if (jj == jme32){
          #pragma unroll
          for (int r = 0; r < 16; ++r){
            const int krow = (r & 3) + 8 * (r >> 2) + 4 * hi;
            if (krow > l31) s[r] = -3.0e38f;
          }
        }

        #pragma unroll
        for (int r = 0; r < 16; ++r) s[r] = exp2f(s[r]);
        {
          float t0 = (s[0] + s[1]) + (s[2] + s[3]);
          float t1 = (s[4] + s[5]) + (s[6] + s[7]);
          float t2 = (s[8] + s[9]) + (s[10] + s[11]);
          float t3 = (s[12] + s[13]) + (s[14] + s[15]);
          lsum += (t0 + t1) + (t2 + t3);
        }

        bf16x8 pf[2];
        #pragma unroll
        for (int kb = 0; kb < 2; ++kb){
          const int R0 = kb * 8;
          const unsigned wa0 = cvt_pk_bf16(s[R0],     s[R0 + 1]);
          const unsigned wa1 = cvt_pk_bf16(s[R0 + 2], s[R0 + 3]);
          const unsigned wb0 = cvt_pk_bf16(s[R0 + 4], s[R0 + 5]);
          const unsigned wb1 = cvt_pk_bf16(s[R0 + 6], s[R0 + 7]);
          const int s0 = hi ? (int)wa0 : (int)wb0;
          const int s1 = hi ? (int)wa1 : (int)wb1;
          const int r0 = __shfl_xor(s0, 32, 64);
          const int r1 = __shfl_xor(s1, 32, 64);
          int4 u;
          u.x = hi ? r0 : (int)wa0;
          u.y = hi ? r1 : (int)wa1;
          u.z = hi ? (int)wb0 : r0;
          u.w = hi ? (int)wb1 : r1;
          pf[kb] = *(bf16x8*)&u;
        }

        const u16* VB = Vl[cur][sb];
        __builtin_amdgcn_s_setprio(1);
        #pragma unroll
        for (int db = 0; db < 4; ++db){
          const int r6 = (db & 1) * 32 + l31;   // row in V image
          const int hd = db >> 1;
          #pragma unroll
          for (int kb = 0; kb < 2; ++kb){
            const int sp = ((hd * 4 + kb * 2 + hi) ^ sw7) * 8;
            bf16x8 vf = *(const bf16x8*)(VB + r6 * 64 + sp);
            o[db] = __builtin_amdgcn_mfma_f32_32x32x16_bf16(vf, pf[kb], o[db], 0, 0, 0);
          }
        }
        __builtin_amdgcn_s_setprio(0);
      }
    }
  }

  const float lt = lsum + __shfl_xor(lsum, 32, 64);
  const float inv = 1.0f / lt;
  u16* op = aout + (size_t)(b * TT + qg) * HID + h * 128;
  #pragma unroll
  for (int db = 0; db < 4; ++db)
    #pragma unroll
    for (int rq = 0; rq < 4; ++rq){
      ushort4 pk;
      pk.x = f2bf(o[db][rq * 4 + 0] * inv);
      pk.y = f2bf(o[db][rq * 4 + 1] * inv);
      pk.z = f2bf(o[db][rq * 4 + 2] * inv);
      pk.w = f2bf(o[db][rq * 4 + 3] * inv);
      *(ushort4*)(op + db * 32 + rq * 8 + hi * 4) = pk;
    }
}

// ---------------- host launch ----------------
extern "C" void kernel_launch(void* const* d_in, const int* in_sizes, int n_in,
                              void* d_out, int out_size, void* d_ws, size_t ws_size,
                              hipStream_t stream)
{
  (void)in_sizes; (void)n_in; (void)out_size; (void)ws_size;
  const float* hs    = (const float*)d_in[0];
  const float* w_qkv = (const float*)d_in[1];
  const float* w_out = (const float*)d_in[2];
  const float* b_out = (const float*)d_in[3];
  float* out = (float*)d_out;

  char* ws = (char*)d_ws;
  u16* qk_bf   = (u16*)(ws);
  u16* vt2_bf  = (u16*)(ws + 67108864);
  u16* wout_bf = (u16*)(ws + 100663296);
  u16* hs_bf   = (u16*)(ws + 109051904);
  u16* attn_bf = hs_bf;
  u16* wqkv_bf = (u16*)(ws + 142606336);

  cvt_all<<<4096, 256, 0, stream>>>(hs,    hs_bf,   (BT * HID) / 4,
                                    w_qkv, wqkv_bf, (QKV_N * HID) / 4,
                                    w_out, wout_bf, (HID * 2048) / 4);

  gemm256<1><<<(BT / 256) * (QKV_N / 256), 512, 0, stream>>>(
      hs_bf, wqkv_bf, qk_bf, nullptr, nullptr, vt2_bf, BT, QKV_N, HID);

  attn<<<dim3(64, 16), 256, 0, stream>>>(qk_bf, vt2_bf, attn_bf);

  gemm256<0><<<(BT / 256) * (HID / 256), 512, 0, stream>>>(
      attn_bf, wout_bf, nullptr, out, b_out, nullptr, BT, HID, HID);
}

// Round 13
// 362.642 us; speedup vs baseline: 1.0134x; 1.0134x over previous
//
#include <hip/hip_runtime.h>
#include <hip/hip_bf16.h>
#include <stdint.h>

#define HID   2048
#define NH    16
#define QKV_N 6144   // 16*(2*128+128)
#define QKP   4096   // pitch of qk_bf (Q|K only)
#define BT    8192   // B*T
#define TT    2048   // T

typedef short bf16x8  __attribute__((ext_vector_type(8)));
typedef float f32x4   __attribute__((ext_vector_type(4)));
typedef float f32x16  __attribute__((ext_vector_type(16)));
typedef unsigned short u16;

__device__ __forceinline__ u16 f2bf(float f){
  union { float f; unsigned u; } v; v.f = f;
  unsigned r = 0x7fffu + ((v.u >> 16) & 1u);
  return (u16)((v.u + r) >> 16);
}
__device__ __forceinline__ float bf2f(u16 x){
  union { unsigned u; float f; } v; v.u = ((unsigned)x) << 16;
  return v.f;
}
__device__ __forceinline__ unsigned cvt_pk_bf16(float lo, float hi){
  unsigned r;
  asm("v_cvt_pk_bf16_f32 %0, %1, %2" : "=v"(r) : "v"(lo), "v"(hi));
  return r;
}

typedef __attribute__((address_space(3))) void lds_vt;
typedef const __attribute__((address_space(1))) void gbl_vt;

__device__ __forceinline__ void gload16(const void* g, void* l){
  __builtin_amdgcn_global_load_lds((gbl_vt*)g, (lds_vt*)l, 16, 0, 0);
}

#define FENCE() asm volatile("" ::: "memory")
#define SYNC()  { FENCE(); __builtin_amdgcn_s_barrier(); FENCE(); }

// ---------------- fused fp32 -> bf16 convert (3 arrays, 1 launch) ----------------
__global__ __launch_bounds__(256) void cvt_all(const float* __restrict__ in1, u16* __restrict__ o1, int n1,
                                               const float* __restrict__ in2, u16* __restrict__ o2, int n2,
                                               const float* __restrict__ in3, u16* __restrict__ o3, int n3){
  int i = blockIdx.x * blockDim.x + threadIdx.x;
  const int stride = gridDim.x * blockDim.x;
  const int ntot = n1 + n2 + n3;
  for (; i < ntot; i += stride){
    const float* ip; u16* op; int k;
    if (i < n1)            { ip = in1; op = o1; k = i; }
    else if (i < n1 + n2)  { ip = in2; op = o2; k = i - n1; }
    else                   { ip = in3; op = o3; k = i - n1 - n2; }
    float4 v = ((const float4*)ip)[k];
    ushort4 o;
    o.x = f2bf(v.x); o.y = f2bf(v.y); o.z = f2bf(v.z); o.w = f2bf(v.w);
    ((ushort4*)op)[k] = o;
  }
}

// ---------------- 256x256 8-phase bf16 GEMM, C = A * B^T ----------------
// 16x16x32 core (known-good: 186us, MfmaUtil 50%, 0 conflicts).
// MODE 0: fp32 out + bias (pitch N). MODE 1: bf16 out, Q/K tiles (n0<4096) ->
// Cb pitch 4096; V tiles (n0>=4096) -> vt2 transposed-swizzled image (fused vtrans).
template<int MODE>
__global__ __launch_bounds__(512, 2) void gemm256(const u16* __restrict__ A,
                                                  const u16* __restrict__ Bm,
                                                  u16* __restrict__ Cb,
                                                  float* __restrict__ Cf,
                                                  const float* __restrict__ bias,
                                                  u16* __restrict__ vt2,
                                                  int M, int N, int K)
{
  __shared__ u16 lds[4 * 256 * 64];   // 128 KiB
  u16* const Abuf[2] = { lds,          lds + 16384 };
  u16* const Bbuf[2] = { lds + 32768,  lds + 49152 };

  const int tid  = threadIdx.x;
  const int w    = tid >> 6;
  const int lane = tid & 63;
  const int wm   = w >> 2;
  const int wn   = w & 3;
  const int lr   = lane & 15;
  const int lg   = lane >> 4;

  int bid = blockIdx.x;
  { int qq = gridDim.x >> 3; bid = (bid & 7) * qq + (bid >> 3); }
  const int ntile = N >> 8;
  const int m0 = (bid / ntile) << 8;
  const int n0 = (bid % ntile) << 8;

  const int rS = tid >> 3;
  const int cS = ((tid & 7) ^ (rS & 7)) * 8;
  const u16* gA = A  + (size_t)(m0 + rS) * K + cS;
  const u16* gB = Bm + (size_t)(n0 + rS) * K + cS;
  const int wds = w * 512;

  f32x4 acc[8][4] = {};
  bf16x8 aq[2][2], bq[4][2];

  auto stgA = [&](int buf, int half, int kt){
    const u16* s = gA + (size_t)(half * 128) * K + (size_t)kt * 64;
    gload16(s,                  Abuf[buf] + half * 8192 + wds);
    gload16(s + (size_t)64 * K, Abuf[buf] + half * 8192 + 4096 + wds);
  };
  auto stgB = [&](int buf, int half, int kt){
    const u16* s = gB + (size_t)(half * 128) * K + (size_t)kt * 64;
    gload16(s,                  Bbuf[buf] + half * 8192 + wds);
    gload16(s + (size_t)64 * K, Bbuf[buf] + half * 8192 + 4096 + wds);
  };
  auto loadA = [&](const u16* ab, int q){
    #pragma unroll
    for (int kk = 0; kk < 2; ++kk){
      #pragma unroll
      for (int mf2 = 0; mf2 < 2; ++mf2){
        int row = wm * 128 + (q * 2 + mf2) * 16 + lr;
        int blk = (kk * 4 + lg) ^ (lr & 7);
        aq[mf2][kk] = *(const bf16x8*)(ab + row * 64 + blk * 8);
      }
    }
  };
  auto loadB = [&](const u16* bb){
    #pragma unroll
    for (int nf = 0; nf < 4; ++nf){
      #pragma unroll
      for (int kk = 0; kk < 2; ++kk){
        int row = wn * 64 + nf * 16 + lr;
        int blk = (kk * 4 + lg) ^ (lr & 7);
        bq[nf][kk] = *(const bf16x8*)(bb + row * 64 + blk * 8);
      }
    }
  };

#define MFMAQ(Q) do {                                                         \
    __builtin_amdgcn_s_setprio(1);                                            \
    _Pragma("unroll")                                                         \
    for (int kk = 0; kk < 2; ++kk){                                           \
      _Pragma("unroll")                                                       \
      for (int mf2 = 0; mf2 < 2; ++mf2){                                      \
        _Pragma("unroll")                                                     \
        for (int nf = 0; nf < 4; ++nf)                                        \
          acc[(Q)*2+mf2][nf] = __builtin_amdgcn_mfma_f32_16x16x32_bf16(       \
              aq[mf2][kk], bq[nf][kk], acc[(Q)*2+mf2][nf], 0, 0, 0);          \
      }                                                                       \
    }                                                                         \
    __builtin_amdgcn_s_setprio(0);                                            \
  } while (0)

  stgA(0, 0, 0); stgA(0, 1, 0);
  stgB(0, 0, 0); stgB(0, 1, 0);
  stgB(1, 0, 1); stgB(1, 1, 1);
  asm volatile("s_waitcnt vmcnt(4)" ::: "memory");
  SYNC();

  const int NI = K >> 7;
  for (int it = 0; it < NI; ++it){
    const int t = it * 2;
    const bool lastI = (it == NI - 1);

    loadB(Bbuf[0]);
    loadA(Abuf[0], 0);
    stgA(1, 0, t + 1);
    SYNC(); MFMAQ(0); SYNC();

    loadA(Abuf[0], 1);
    stgA(1, 1, t + 1);
    SYNC(); MFMAQ(1); SYNC();

    loadA(Abuf[0], 2);
    if (!lastI) stgB(0, 0, t + 2);
    SYNC(); MFMAQ(2); SYNC();

    loadA(Abuf[0], 3);
    if (!lastI) stgB(0, 1, t + 2);
    SYNC(); MFMAQ(3);
    if (lastI) asm volatile("s_waitcnt vmcnt(0)" ::: "memory");
    else       asm volatile("s_waitcnt vmcnt(4)" ::: "memory");
    SYNC();

    loadB(Bbuf[1]);
    loadA(Abuf[1], 0);
    if (!lastI) stgA(0, 0, t + 2);
    SYNC(); MFMAQ(0); SYNC();

    loadA(Abuf[1], 1);
    if (!lastI) stgA(0, 1, t + 2);
    SYNC(); MFMAQ(1); SYNC();

    loadA(Abuf[1], 2);
    if (!lastI) stgB(1, 0, t + 3);
    SYNC(); MFMAQ(2); SYNC();

    loadA(Abuf[1], 3);
    if (!lastI) stgB(1, 1, t + 3);
    SYNC(); MFMAQ(3);
    if (!lastI) asm volatile("s_waitcnt vmcnt(4)" ::: "memory");
    SYNC();
  }
#undef MFMAQ

  // epilogue: D layout col = lane&15, row = (lane>>4)*4 + r
  const int orow = m0 + wm * 128 + lg * 4;
  const int ocol = n0 + wn * 64 + lr;

  if (MODE == 1 && n0 >= 4096){
    // fused V-transpose: write vt2[bh][t5] image (exact inverse of attn's reader)
    #pragma unroll
    for (int nf = 0; nf < 4; ++nf){
      const int c   = ocol + nf * 16 - 4096;   // 0..2047
      const int h2  = c >> 7;
      const int d   = c & 127;
      const int r64 = d & 63;
      const int hd  = d >> 6;
      #pragma unroll
      for (int mf = 0; mf < 8; ++mf)
        #pragma unroll
        for (int r = 0; r < 4; ++r){
          const int row = orow + mf * 16 + r;       // t_global
          const int bb  = row >> 11;
          const int t   = row & 2047;
          const int t5  = t >> 5;
          const int kv  = t & 31;
          const int sl  = hd * 4 + (kv >> 3);
          const int sp  = sl ^ (r64 & 7);
          vt2[(size_t)((bb * 16 + h2) * 64 + t5) * 4096 + r64 * 64 + sp * 8 + (kv & 7)]
              = f2bf(acc[mf][nf][r]);
        }
    }
  } else {
    #pragma unroll
    for (int mf = 0; mf < 8; ++mf)
      #pragma unroll
      for (int nf = 0; nf < 4; ++nf)
        #pragma unroll
        for (int r = 0; r < 4; ++r){
          int row = orow + mf * 16 + r;
          int col = ocol + nf * 16;
          float v = acc[mf][nf][r];
          if (MODE == 1)
            Cb[(size_t)row * QKP + col] = f2bf(v);
          else
            Cf[(size_t)row * N + col] = v + bias[col];
        }
  }
}

// ---------------- causal flash attention, swapped 32x32, KVBLK=32 ----------------
// (round-11 configuration: triple-buffered 48KB, 3 blocks/CU, depth-2 prefetch,
//  split QK chains — measured optimum of this structure family)
__global__ __launch_bounds__(256, 3) void attn(const u16* __restrict__ qk,
                                               const u16* __restrict__ vt2,
                                               u16* __restrict__ aout)
{
  __shared__ u16 Kl[3][32 * 128];   // 24KB
  __shared__ u16 Vl[3][64 * 64];    // 24KB

  const int qt = 15 - (int)blockIdx.y;
  const int bh = blockIdx.x;
  const int b = bh >> 4, h = bh & 15;
  const int tid  = threadIdx.x;
  const int w    = tid >> 6;
  const int lane = tid & 63;
  const int l31  = lane & 31;
  const int hi   = lane >> 5;
  const int sw7  = l31 & 7;

  const int qg = qt * 128 + w * 32 + l31;   // this lane's q row
  const float sc2 = 0.08838834764831845f * 1.4426950408889634f;

  bf16x8 qf[8];
  {
    const u16* qp = qk + (size_t)(b * TT + qg) * QKP + h * 128 + hi * 8;
    #pragma unroll
    for (int s = 0; s < 8; ++s){
      bf16x8 raw = *(const bf16x8*)(qp + s * 16);
      unsigned pk[4];
      #pragma unroll
      for (int p2 = 0; p2 < 4; ++p2)
        pk[p2] = cvt_pk_bf16(bf2f((u16)raw[2 * p2]) * sc2,
                             bf2f((u16)raw[2 * p2 + 1]) * sc2);
      int4 u = { (int)pk[0], (int)pk[1], (int)pk[2], (int)pk[3] };
      qf[s] = *(bf16x8*)&u;
    }
  }

  f32x16 o[4] = {};
  float lsum = 0.f;

  const u16* ksrc = qk + (size_t)(b * TT + (tid >> 4)) * QKP + 2048 + h * 128
                    + (((tid & 15) ^ ((tid >> 4) & 7)) * 8);
  const u16* vsrc = vt2 + (size_t)bh * (64 * 4096) + tid * 8;

  auto stage = [&](int buf, int j){
    const u16* ks = ksrc + (size_t)(j * 32) * QKP;
    gload16(ks,                    &Kl[buf][tid * 8]);
    gload16(ks + (size_t)16 * QKP, &Kl[buf][2048 + tid * 8]);
    const u16* vs = vsrc + (size_t)j * 4096;
    gload16(vs,        &Vl[buf][tid * 8]);
    gload16(vs + 2048, &Vl[buf][2048 + tid * 8]);
  };

  const int NT  = 4 * qt + 4;       // >= 4
  const int jme = qt * 4 + w;       // last tile this wave computes (diagonal)
  stage(0, 0);
  stage(1, 1);

  int cur = 0;
  for (int j = 0; j < NT; ++j){
    SYNC();                                   // B1: buf[(j+2)%3]'s readers done
    if (j + 2 < NT){
      int nb = cur + 2; if (nb >= 3) nb -= 3;
      stage(nb, j + 2);
      asm volatile("s_waitcnt vmcnt(8)" ::: "memory");   // stage(j) landed
    } else if (j + 1 < NT){
      asm volatile("s_waitcnt vmcnt(4)" ::: "memory");
    } else {
      asm volatile("s_waitcnt vmcnt(0)" ::: "memory");
    }
    SYNC();                                   // B2: buf[cur] visible

    if (j <= jme){
      f32x16 sa = {}, sb = {};
      const u16* KB = Kl[cur];
      __builtin_amdgcn_s_setprio(1);
      #pragma unroll
      for (int sl = 0; sl < 4; ++sl){
        const int spa = ((sl * 2 + hi) ^ sw7) * 8;
        const int spb = (((sl + 4) * 2 + hi) ^ sw7) * 8;
        bf16x8 ka = *(const bf16x8*)(KB + l31 * 128 + spa);
        bf16x8 kb2 = *(const bf16x8*)(KB + l31 * 128 + spb);
        sa = __builtin_amdgcn_mfma_f32_32x32x16_bf16(ka,  qf[sl],     sa, 0, 0, 0);
        sb = __builtin_amdgcn_mfma_f32_32x32x16_bf16(kb2, qf[sl + 4], sb, 0, 0, 0);
      }
      __builtin_amdgcn_s_setprio(0);

      f32x16 s;
      #pragma unroll
      for (int r = 0; r < 16; ++r) s[r] = sa[r] + sb[r];

      if (j == jme){
        #pragma unroll
        for (int r = 0; r < 16; ++r){
          const int krow = (r & 3) + 8 * (r >> 2) + 4 * hi;
          if (krow > l31) s[r] = -3.0e38f;
        }
      }

      #pragma unroll
      for (int r = 0; r < 16; ++r) s[r] = exp2f(s[r]);
      {
        float t0 = (s[0] + s[1]) + (s[2] + s[3]);
        float t1 = (s[4] + s[5]) + (s[6] + s[7]);
        float t2 = (s[8] + s[9]) + (s[10] + s[11]);
        float t3 = (s[12] + s[13]) + (s[14] + s[15]);
        lsum += (t0 + t1) + (t2 + t3);
      }

      bf16x8 pf[2];
      #pragma unroll
      for (int kb = 0; kb < 2; ++kb){
        const int R0 = kb * 8;
        const unsigned wa0 = cvt_pk_bf16(s[R0],     s[R0 + 1]);
        const unsigned wa1 = cvt_pk_bf16(s[R0 + 2], s[R0 + 3]);
        const unsigned wb0 = cvt_pk_bf16(s[R0 + 4], s[R0 + 5]);
        const unsigned wb1 = cvt_pk_bf16(s[R0 + 6], s[R0 + 7]);
        const int s0 = hi ? (int)wa0 : (int)wb0;
        const int s1 = hi ? (int)wa1 : (int)wb1;
        const int r0 = __shfl_xor(s0, 32, 64);
        const int r1 = __shfl_xor(s1, 32, 64);
        int4 u;
        u.x = hi ? r0 : (int)wa0;
        u.y = hi ? r1 : (int)wa1;
        u.z = hi ? (int)wb0 : r0;
        u.w = hi ? (int)wb1 : r1;
        pf[kb] = *(bf16x8*)&u;
      }

      const u16* VB = Vl[cur];
      __builtin_amdgcn_s_setprio(1);
      #pragma unroll
      for (int db = 0; db < 4; ++db){
        const int r6 = (db & 1) * 32 + l31;   // row in V image
        const int hd = db >> 1;
        #pragma unroll
        for (int kb = 0; kb < 2; ++kb){
          const int sp = ((hd * 4 + kb * 2 + hi) ^ sw7) * 8;
          bf16x8 vf = *(const bf16x8*)(VB + r6 * 64 + sp);
          o[db] = __builtin_amdgcn_mfma_f32_32x32x16_bf16(vf, pf[kb], o[db], 0, 0, 0);
        }
      }
      __builtin_amdgcn_s_setprio(0);
    }

    ++cur; if (cur == 3) cur = 0;
  }

  const float lt = lsum + __shfl_xor(lsum, 32, 64);
  const float inv = 1.0f / lt;
  u16* op = aout + (size_t)(b * TT + qg) * HID + h * 128;
  #pragma unroll
  for (int db = 0; db < 4; ++db)
    #pragma unroll
    for (int rq = 0; rq < 4; ++rq){
      ushort4 pk;
      pk.x = f2bf(o[db][rq * 4 + 0] * inv);
      pk.y = f2bf(o[db][rq * 4 + 1] * inv);
      pk.z = f2bf(o[db][rq * 4 + 2] * inv);
      pk.w = f2bf(o[db][rq * 4 + 3] * inv);
      *(ushort4*)(op + db * 32 + rq * 8 + hi * 4) = pk;
    }
}

// ---------------- host launch ----------------
extern "C" void kernel_launch(void* const* d_in, const int* in_sizes, int n_in,
                              void* d_out, int out_size, void* d_ws, size_t ws_size,
                              hipStream_t stream)
{
  (void)in_sizes; (void)n_in; (void)out_size; (void)ws_size;
  const float* hs    = (const float*)d_in[0];
  const float* w_qkv = (const float*)d_in[1];
  const float* w_out = (const float*)d_in[2];
  const float* b_out = (const float*)d_in[3];
  float* out = (float*)d_out;

  char* ws = (char*)d_ws;
  u16* qk_bf   = (u16*)(ws);
  u16* vt2_bf  = (u16*)(ws + 67108864);
  u16* wout_bf = (u16*)(ws + 100663296);
  u16* hs_bf   = (u16*)(ws + 109051904);
  u16* attn_bf = hs_bf;
  u16* wqkv_bf = (u16*)(ws + 142606336);

  cvt_all<<<4096, 256, 0, stream>>>(hs,    hs_bf,   (BT * HID) / 4,
                                    w_qkv, wqkv_bf, (QKV_N * HID) / 4,
                                    w_out, wout_bf, (HID * 2048) / 4);

  gemm256<1><<<(BT / 256) * (QKV_N / 256), 512, 0, stream>>>(
      hs_bf, wqkv_bf, qk_bf, nullptr, nullptr, vt2_bf, BT, QKV_N, HID);

  attn<<<dim3(64, 16), 256, 0, stream>>>(qk_bf, vt2_bf, attn_bf);

  gemm256<0><<<(BT / 256) * (HID / 256), 512, 0, stream>>>(
      attn_bf, wout_bf, nullptr, out, b_out, nullptr, BT, HID, HID);
}